// Round 5
// baseline (329.889 us; speedup 1.0000x reference)
//
#include <hip/hip_runtime.h>
#include <hip/hip_bf16.h>

typedef short s16x8 __attribute__((ext_vector_type(8)));
typedef float f32x4 __attribute__((ext_vector_type(4)));

#define MFMA_BF16(A, B, C) __builtin_amdgcn_mfma_f32_16x16x32_bf16(A, B, C, 0, 0, 0)

constexpr int Bn = 4, Tn = 2048, Cn = 1024, Hn = 16, Dn = 64;
constexpr int Mn = Bn * Tn;      // 8192
constexpr int Nqkv = 3 * Cn;     // 3072

__device__ __forceinline__ ushort f2bfu(float f) {
    __hip_bfloat16 h = __float2bfloat16(f);
    return *reinterpret_cast<ushort*>(&h);
}

// async global->LDS, 16B per lane; LDS dest = wave-uniform base + lane*16.
__device__ __forceinline__ void gl_lds16(const void* g, void* l) {
    __builtin_amdgcn_global_load_lds(
        (const __attribute__((address_space(1))) void*)(uintptr_t)g,
        (__attribute__((address_space(3))) void*)(uint32_t)(uintptr_t)l,
        16, 0, 0);
}

// ---------------------------------------------------------------------------
// fp32 -> bf16 elementwise (x)
// ---------------------------------------------------------------------------
__global__ __launch_bounds__(256) void conv_bf16_kernel(
    const float* __restrict__ src, ushort* __restrict__ dst, int n4)
{
    int i = blockIdx.x * blockDim.x + threadIdx.x;
    int stride = gridDim.x * blockDim.x;
    for (; i < n4; i += stride) {
        float4 v = ((const float4*)src)[i];
        ushort4 o;
        o.x = f2bfu(v.x); o.y = f2bfu(v.y); o.z = f2bfu(v.z); o.w = f2bfu(v.w);
        ((ushort4*)dst)[i] = o;
    }
}

// ---------------------------------------------------------------------------
// W [K][N] fp32  ->  Wt [N][K] bf16   (64x64 tiles via LDS)
// ---------------------------------------------------------------------------
__global__ __launch_bounds__(256) void transpose_cvt_kernel(
    const float* __restrict__ W, ushort* __restrict__ Wt, int K, int N)
{
    __shared__ __align__(16) float Ls[64][68];
    const int t = threadIdx.x;
    const int n0 = blockIdx.x * 64, k0 = blockIdx.y * 64;
#pragma unroll
    for (int p = 0; p < 4; ++p) {
        int r = (t >> 4) + p * 16;
        int c = (t & 15) * 4;
        *(float4*)&Ls[r][c] = *(const float4*)&W[(size_t)(k0 + r) * N + n0 + c];
    }
    __syncthreads();
    const int n = t >> 2;
    const int ks = (t & 3) * 16;
    union { ushort s[16]; uint4 u[2]; } tmp;
#pragma unroll
    for (int j = 0; j < 16; ++j) tmp.s[j] = f2bfu(Ls[ks + j][n]);
    uint4* dp = (uint4*)&Wt[(size_t)(n0 + n) * K + k0 + ks];
    dp[0] = tmp.u[0];
    dp[1] = tmp.u[1];
}

// ---------------------------------------------------------------------------
// QKV GEMM, m97-style: global_load_lds(16B) staging into unpadded [128][64]
// LDS with XOR chunk swizzle (phys_chunk = logical_chunk ^ (row&7)).
// ---------------------------------------------------------------------------
__global__ __launch_bounds__(256) void qkv_gemm_mfma(
    const ushort* __restrict__ A, const ushort* __restrict__ Bt,
    const float* __restrict__ bias,
    ushort* __restrict__ Qo, ushort* __restrict__ Ko, ushort* __restrict__ Vo)
{
    __shared__ __align__(16) ushort As[128 * 64];
    __shared__ __align__(16) ushort Bs[128 * 64];
    const int tid = threadIdx.x;
    const int m0 = blockIdx.x * 128, n0 = blockIdx.y * 128;
    const int w = tid >> 6, lane = tid & 63, l15 = lane & 15, qd = lane >> 4;
    const int wm = (w >> 1) * 64, wn = (w & 1) * 64;
    const int lrow = lane >> 3;
    const int lchunk = (lane & 7) ^ (lrow & 7);

    const ushort* gA = A + (size_t)(m0 + w * 32 + lrow) * Cn + lchunk * 8;
    const ushort* gB = Bt + (size_t)(n0 + w * 32 + lrow) * Cn + lchunk * 8;
    ushort* lA = &As[(w * 32) * 64];
    ushort* lB = &Bs[(w * 32) * 64];

    f32x4 acc[4][4] = {};

    for (int k0 = 0; k0 < Cn; k0 += 64) {
        __syncthreads();
#pragma unroll
        for (int t = 0; t < 4; ++t) {
            gl_lds16(gA + (size_t)t * 8 * Cn + k0, lA + t * 8 * 64);
            gl_lds16(gB + (size_t)t * 8 * Cn + k0, lB + t * 8 * 64);
        }
        __syncthreads();
#pragma unroll
        for (int ks = 0; ks < 2; ++ks) {
            const int xs = (((ks * 4 + qd) ^ (l15 & 7))) * 8;
            s16x8 af[4], bfr[4];
#pragma unroll
            for (int i = 0; i < 4; ++i) {
                af[i]  = *(const s16x8*)&As[(wm + i * 16 + l15) * 64 + xs];
                bfr[i] = *(const s16x8*)&Bs[(wn + i * 16 + l15) * 64 + xs];
            }
#pragma unroll
            for (int mt = 0; mt < 4; ++mt)
#pragma unroll
                for (int nt = 0; nt < 4; ++nt)
                    acc[mt][nt] = MFMA_BF16(af[mt], bfr[nt], acc[mt][nt]);
        }
    }

#pragma unroll
    for (int nt = 0; nt < 4; ++nt) {
        int n_g = n0 + wn + nt * 16 + l15;
        float bv = bias[n_g];
        int sel = n_g >> 10;
        int h = (n_g >> 6) & 15;
        int d = n_g & 63;
        ushort* O = (sel == 0) ? Qo : ((sel == 1) ? Ko : Vo);
#pragma unroll
        for (int mt = 0; mt < 4; ++mt) {
#pragma unroll
            for (int r = 0; r < 4; ++r) {
                int m_g = m0 + wm + mt * 16 + qd * 4 + r;
                int b = m_g >> 11, t = m_g & 2047;
                O[(((size_t)(b * Hn + h) * Tn + t) << 6) + d] =
                    f2bfu(acc[mt][nt][r] + bv);
            }
        }
    }
}

// ---------------------------------------------------------------------------
// Transposed MFMA flash attention, paired q-tiles for perfect load balance.
// Block bx handles q-tiles {bx, 31-bx}: (bx+1) + (32-bx) = 33 kt-units for
// every block -> grid = 16 x 64 = 1024 identical blocks = 4/CU.
// LDS: unpadded [64][64] + XOR chunk swizzle; addr(row, col) =
//   row*64 + ((col/8 ^ (row&7))*8) + col%8  -- all access classes balanced.
// ---------------------------------------------------------------------------
__global__ __launch_bounds__(256) void attn_mfma(
    const ushort* __restrict__ Q, const ushort* __restrict__ K,
    const ushort* __restrict__ V, ushort* __restrict__ Y)
{
    __shared__ __align__(16) ushort Qs[64 * 64];  // Q tile; wave rows reused for P^T
    __shared__ __align__(16) ushort Ks[64 * 64];  // [key][d]
    __shared__ __align__(16) ushort Vt[64 * 64];  // [d][key]

    const int tid = threadIdx.x;
    const int bx = blockIdx.x, bh = blockIdx.y;
    const int w = tid >> 6, lane = tid & 63, l15 = lane & 15, qd = lane >> 4;
    const size_t base = (size_t)bh * Tn * Dn;
    const int srow = tid >> 2;          // 0..63
    const int c0 = (tid & 3) * 2;       // uint4 chunks c0, c0+1
    const int sw0 = srow * 64 + ((c0 ^ (srow & 7)) * 8);
    const int sw1 = srow * 64 + (((c0 + 1) ^ (srow & 7)) * 8);
    const int vk = (tid & 15) * 4, vd = (tid >> 4) * 4;
    const int q_l = w * 16 + l15;
    const int frow = (w * 16 + l15) * 64;
    const int fx0 = ((0 * 4 + qd) ^ (l15 & 7)) * 8;   // ks=0 fragment offset
    const int fx1 = ((1 * 4 + qd) ^ (l15 & 7)) * 8;   // ks=1 fragment offset
    constexpr float SC = 0.125f * 1.44269504089f;     // scale * log2(e)

    const int b = bh >> 4, h = bh & 15;

#pragma unroll
    for (int half = 0; half < 2; ++half) {
        const int qt = half ? (31 - bx) : bx;
        __syncthreads();   // Qs free (previous half's P reads complete)
        // stage Q tile
        {
            const uint4* gq = (const uint4*)(Q + base + (size_t)(qt * 64 + srow) * Dn + c0 * 8);
            uint4 q0 = gq[0], q1 = gq[1];
            *(uint4*)&Qs[sw0] = q0;
            *(uint4*)&Qs[sw1] = q1;
        }
        __syncthreads();
        s16x8 qf0 = *(const s16x8*)&Qs[frow + fx0];
        s16x8 qf1 = *(const s16x8*)&Qs[frow + fx1];

        float m_run = -1e30f, l_run = 0.f;
        f32x4 o[4] = {};   // O^T[d=dt*16+qd*4+r][q=l15]

        for (int kt = 0; kt <= qt; ++kt) {
            __syncthreads();   // prev-iter Ks/Vt reads done
            {
                const uint4* gk = (const uint4*)(K + base + (size_t)(kt * 64 + srow) * Dn + c0 * 8);
                uint4 k0 = gk[0], k1 = gk[1];
                *(uint4*)&Ks[sw0] = k0;
                *(uint4*)&Ks[sw1] = k1;
                // V 4x4 in-register transpose -> Vt[d][key]
                const ushort* gv = V + base + (size_t)(kt * 64 + vk) * Dn + vd;
                ushort4 v0 = *(const ushort4*)(gv);
                ushort4 v1 = *(const ushort4*)(gv + Dn);
                ushort4 v2 = *(const ushort4*)(gv + 2 * Dn);
                ushort4 v3 = *(const ushort4*)(gv + 3 * Dn);
                ushort4 t0, t1, t2, t3;
                t0.x = v0.x; t0.y = v1.x; t0.z = v2.x; t0.w = v3.x;
                t1.x = v0.y; t1.y = v1.y; t1.z = v2.y; t1.w = v3.y;
                t2.x = v0.z; t2.y = v1.z; t2.z = v2.z; t2.w = v3.z;
                t3.x = v0.w; t3.y = v1.w; t3.z = v2.w; t3.w = v3.w;
                const int vc = vk >> 3, vo = vk & 7;
#pragma unroll
                for (int j = 0; j < 4; ++j) {
                    int r = vd + j;
                    ushort4 tj = (j == 0) ? t0 : (j == 1) ? t1 : (j == 2) ? t2 : t3;
                    *(ushort4*)&Vt[r * 64 + ((vc ^ (r & 7)) * 8) + vo] = tj;
                }
            }
            __syncthreads();

            // S^T = K·Q^T : lane(qd,l15) reg(nt,r) = S^T[key=nt*16+qd*4+r][q=l15]
            f32x4 s[4] = {};
#pragma unroll
            for (int nt = 0; nt < 4; ++nt) {
                s16x8 kf = *(const s16x8*)&Ks[(nt * 16 + l15) * 64 + fx0];
                s[nt] = MFMA_BF16(kf, qf0, s[nt]);
            }
#pragma unroll
            for (int nt = 0; nt < 4; ++nt) {
                s16x8 kf = *(const s16x8*)&Ks[(nt * 16 + l15) * 64 + fx1];
                s[nt] = MFMA_BF16(kf, qf1, s[nt]);
            }
#pragma unroll
            for (int nt = 0; nt < 4; ++nt)
#pragma unroll
                for (int r = 0; r < 4; ++r) s[nt][r] *= SC;   // scale*log2e

            if (kt == qt) {
#pragma unroll
                for (int nt = 0; nt < 4; ++nt)
#pragma unroll
                    for (int r = 0; r < 4; ++r)
                        if (nt * 16 + qd * 4 + r > q_l) s[nt][r] = -1e30f;
            }

            // online softmax over keys (exp2 domain): 15 in-lane + 2 shuffles
            float mx = s[0][0];
#pragma unroll
            for (int nt = 0; nt < 4; ++nt)
#pragma unroll
                for (int r = 0; r < 4; ++r) mx = fmaxf(mx, s[nt][r]);
            mx = fmaxf(mx, __shfl_xor(mx, 16));
            mx = fmaxf(mx, __shfl_xor(mx, 32));
            float m_new = fmaxf(m_run, mx);
            float alpha = exp2f(m_run - m_new);
            float ls = 0.f;
#pragma unroll
            for (int nt = 0; nt < 4; ++nt)
#pragma unroll
                for (int r = 0; r < 4; ++r) {
                    float p = exp2f(s[nt][r] - m_new);
                    s[nt][r] = p;
                    ls += p;
                }
            ls += __shfl_xor(ls, 16);
            ls += __shfl_xor(ls, 32);
            l_run = l_run * alpha + ls;
            m_run = m_new;
#pragma unroll
            for (int dt = 0; dt < 4; ++dt)
#pragma unroll
                for (int r = 0; r < 4; ++r) o[dt][r] *= alpha;

            // P^T -> wave-private LDS rows (key-consecutive regs -> b64 packs)
#pragma unroll
            for (int nt = 0; nt < 4; ++nt) {
                ushort4 pk;
                pk.x = f2bfu(s[nt][0]); pk.y = f2bfu(s[nt][1]);
                pk.z = f2bfu(s[nt][2]); pk.w = f2bfu(s[nt][3]);
                const int pc = 2 * nt + (qd >> 1), po = (qd & 1) * 4;
                *(ushort4*)&Qs[frow + ((pc ^ (l15 & 7)) * 8) + po] = pk;
            }

            // O^T += V^T · P^T
            {
                s16x8 pb = *(const s16x8*)&Qs[frow + fx0];
#pragma unroll
                for (int dt = 0; dt < 4; ++dt) {
                    s16x8 vf = *(const s16x8*)&Vt[(dt * 16 + l15) * 64 + fx0];
                    o[dt] = MFMA_BF16(vf, pb, o[dt]);
                }
                pb = *(const s16x8*)&Qs[frow + fx1];
#pragma unroll
                for (int dt = 0; dt < 4; ++dt) {
                    s16x8 vf = *(const s16x8*)&Vt[(dt * 16 + l15) * 64 + fx1];
                    o[dt] = MFMA_BF16(vf, pb, o[dt]);
                }
            }
        }

        // epilogue: O^T[d][q=l15] -> Y[b, t=q_global, h*64+d]
        const float inv = 1.f / l_run;
        const int t_g = qt * 64 + w * 16 + l15;
        ushort* yp = Y + ((size_t)(b * Tn + t_g)) * Cn + h * Dn + qd * 4;
#pragma unroll
        for (int dt = 0; dt < 4; ++dt) {
            ushort4 pk;
            pk.x = f2bfu(o[dt][0] * inv);
            pk.y = f2bfu(o[dt][1] * inv);
            pk.z = f2bfu(o[dt][2] * inv);
            pk.w = f2bfu(o[dt][3] * inv);
            *(ushort4*)(yp + dt * 16) = pk;
        }
    }
}

// ---------------------------------------------------------------------------
// Proj GEMM: Y [8192][1024] bf16, Wt [1024][1024] bf16 -> out fp32
// ---------------------------------------------------------------------------
__global__ __launch_bounds__(256) void proj_gemm_mfma(
    const ushort* __restrict__ A, const ushort* __restrict__ Bt,
    const float* __restrict__ bias, float* __restrict__ out)
{
    __shared__ __align__(16) ushort As[128 * 64];
    __shared__ __align__(16) ushort Bs[128 * 64];
    const int tid = threadIdx.x;
    const int m0 = blockIdx.x * 128, n0 = blockIdx.y * 128;
    const int w = tid >> 6, lane = tid & 63, l15 = lane & 15, qd = lane >> 4;
    const int wm = (w >> 1) * 64, wn = (w & 1) * 64;
    const int lrow = lane >> 3;
    const int lchunk = (lane & 7) ^ (lrow & 7);

    const ushort* gA = A + (size_t)(m0 + w * 32 + lrow) * Cn + lchunk * 8;
    const ushort* gB = Bt + (size_t)(n0 + w * 32 + lrow) * Cn + lchunk * 8;
    ushort* lA = &As[(w * 32) * 64];
    ushort* lB = &Bs[(w * 32) * 64];

    f32x4 acc[4][4] = {};

    for (int k0 = 0; k0 < Cn; k0 += 64) {
        __syncthreads();
#pragma unroll
        for (int t = 0; t < 4; ++t) {
            gl_lds16(gA + (size_t)t * 8 * Cn + k0, lA + t * 8 * 64);
            gl_lds16(gB + (size_t)t * 8 * Cn + k0, lB + t * 8 * 64);
        }
        __syncthreads();
#pragma unroll
        for (int ks = 0; ks < 2; ++ks) {
            const int xs = (((ks * 4 + qd) ^ (l15 & 7))) * 8;
            s16x8 af[4], bfr[4];
#pragma unroll
            for (int i = 0; i < 4; ++i) {
                af[i]  = *(const s16x8*)&As[(wm + i * 16 + l15) * 64 + xs];
                bfr[i] = *(const s16x8*)&Bs[(wn + i * 16 + l15) * 64 + xs];
            }
#pragma unroll
            for (int mt = 0; mt < 4; ++mt)
#pragma unroll
                for (int nt = 0; nt < 4; ++nt)
                    acc[mt][nt] = MFMA_BF16(af[mt], bfr[nt], acc[mt][nt]);
        }
    }

#pragma unroll
    for (int nt = 0; nt < 4; ++nt) {
        int n_g = n0 + wn + nt * 16 + l15;
        float bv = bias[n_g];
#pragma unroll
        for (int mt = 0; mt < 4; ++mt) {
#pragma unroll
            for (int r = 0; r < 4; ++r) {
                int m_g = m0 + wm + mt * 16 + qd * 4 + r;
                out[(size_t)m_g * Cn + n_g] = acc[mt][nt][r] + bv;
            }
        }
    }
}

// ---------------------------------------------------------------------------
extern "C" void kernel_launch(void* const* d_in, const int* in_sizes, int n_in,
                              void* d_out, int out_size, void* d_ws, size_t ws_size,
                              hipStream_t stream) {
    const float* x      = (const float*)d_in[0];
    const float* W_attn = (const float*)d_in[1];
    const float* b_attn = (const float*)d_in[2];
    const float* W_proj = (const float*)d_in[3];
    const float* b_proj = (const float*)d_in[4];
    float* out = (float*)d_out;

    // ws: Q, K, V [B,H,T,D] bf16, Y [B,T,C] bf16
    constexpr size_t PER = (size_t)Mn * Cn;  // 8388608 elems
    ushort* Qb = (ushort*)d_ws;
    ushort* Kb = Qb + PER;
    ushort* Vb = Kb + PER;
    ushort* Yb = Vb + PER;

    // d_out doubles as pre-pass scratch (23 MB < 33.5 MB), dead before proj:
    ushort* WtA  = (ushort*)d_out;
    ushort* x_bf = WtA + (size_t)Nqkv * Cn;
    ushort* WtP  = Qb;   // reuses Q buffer (dead after attention)

    conv_bf16_kernel<<<1024, 256, 0, stream>>>(x, x_bf, (int)(PER / 4));
    transpose_cvt_kernel<<<dim3(Nqkv / 64, Cn / 64), 256, 0, stream>>>(
        W_attn, WtA, Cn, Nqkv);
    qkv_gemm_mfma<<<dim3(Mn / 128, Nqkv / 128), 256, 0, stream>>>(
        x_bf, WtA, b_attn, Qb, Kb, Vb);
    attn_mfma<<<dim3(16, Bn * Hn), 256, 0, stream>>>(Qb, Kb, Vb, Yb);
    transpose_cvt_kernel<<<dim3(Cn / 64, Cn / 64), 256, 0, stream>>>(
        W_proj, WtP, Cn, Cn);
    proj_gemm_mfma<<<dim3(Mn / 128, Cn / 128), 256, 0, stream>>>(
        Yb, WtP, b_proj, out);
}

// Round 6
// 301.776 us; speedup vs baseline: 1.0932x; 1.0932x over previous
//
#include <hip/hip_runtime.h>
#include <hip/hip_bf16.h>

typedef short s16x8 __attribute__((ext_vector_type(8)));
typedef float f32x4 __attribute__((ext_vector_type(4)));

#define MFMA_BF16(A, B, C) __builtin_amdgcn_mfma_f32_16x16x32_bf16(A, B, C, 0, 0, 0)

constexpr int Bn = 4, Tn = 2048, Cn = 1024, Hn = 16, Dn = 64;
constexpr int Mn = Bn * Tn;      // 8192
constexpr int Nqkv = 3 * Cn;     // 3072
constexpr float SC = 0.125f * 1.44269504089f;  // 1/sqrt(D) * log2(e)

__device__ __forceinline__ ushort f2bfu(float f) {
    __hip_bfloat16 h = __float2bfloat16(f);
    return *reinterpret_cast<ushort*>(&h);
}

// async global->LDS, 16B per lane; LDS dest = wave-uniform base + lane*16.
__device__ __forceinline__ void gl_lds16(const void* g, void* l) {
    __builtin_amdgcn_global_load_lds(
        (const __attribute__((address_space(1))) void*)(uintptr_t)g,
        (__attribute__((address_space(3))) void*)(uint32_t)(uintptr_t)l,
        16, 0, 0);
}

// ---------------------------------------------------------------------------
// fp32 -> bf16 elementwise (x)
// ---------------------------------------------------------------------------
__global__ __launch_bounds__(256) void conv_bf16_kernel(
    const float* __restrict__ src, ushort* __restrict__ dst, int n4)
{
    int i = blockIdx.x * blockDim.x + threadIdx.x;
    int stride = gridDim.x * blockDim.x;
    for (; i < n4; i += stride) {
        float4 v = ((const float4*)src)[i];
        ushort4 o;
        o.x = f2bfu(v.x); o.y = f2bfu(v.y); o.z = f2bfu(v.z); o.w = f2bfu(v.w);
        ((ushort4*)dst)[i] = o;
    }
}

// ---------------------------------------------------------------------------
// W [K][N] fp32  ->  Wt [N][K] bf16   (64x64 tiles via LDS)
// ---------------------------------------------------------------------------
__global__ __launch_bounds__(256) void transpose_cvt_kernel(
    const float* __restrict__ W, ushort* __restrict__ Wt, int K, int N)
{
    __shared__ __align__(16) float Ls[64][68];
    const int t = threadIdx.x;
    const int n0 = blockIdx.x * 64, k0 = blockIdx.y * 64;
#pragma unroll
    for (int p = 0; p < 4; ++p) {
        int r = (t >> 4) + p * 16;
        int c = (t & 15) * 4;
        *(float4*)&Ls[r][c] = *(const float4*)&W[(size_t)(k0 + r) * N + n0 + c];
    }
    __syncthreads();
    const int n = t >> 2;
    const int ks = (t & 3) * 16;
    union { ushort s[16]; uint4 u[2]; } tmp;
#pragma unroll
    for (int j = 0; j < 16; ++j) tmp.s[j] = f2bfu(Ls[ks + j][n]);
    uint4* dp = (uint4*)&Wt[(size_t)(n0 + n) * K + k0 + ks];
    dp[0] = tmp.u[0];
    dp[1] = tmp.u[1];
}

// ---------------------------------------------------------------------------
// QKV GEMM, m97-style staging. Q outputs are pre-scaled by SC (softmax
// scale folded in, exp2 domain) so attention skips 16 v_mul per kt.
// ---------------------------------------------------------------------------
__global__ __launch_bounds__(256) void qkv_gemm_mfma(
    const ushort* __restrict__ A, const ushort* __restrict__ Bt,
    const float* __restrict__ bias,
    ushort* __restrict__ Qo, ushort* __restrict__ Ko, ushort* __restrict__ Vo)
{
    __shared__ __align__(16) ushort As[128 * 64];
    __shared__ __align__(16) ushort Bs[128 * 64];
    const int tid = threadIdx.x;
    const int m0 = blockIdx.x * 128, n0 = blockIdx.y * 128;
    const int w = tid >> 6, lane = tid & 63, l15 = lane & 15, qd = lane >> 4;
    const int wm = (w >> 1) * 64, wn = (w & 1) * 64;
    const int lrow = lane >> 3;
    const int lchunk = (lane & 7) ^ (lrow & 7);

    const ushort* gA = A + (size_t)(m0 + w * 32 + lrow) * Cn + lchunk * 8;
    const ushort* gB = Bt + (size_t)(n0 + w * 32 + lrow) * Cn + lchunk * 8;
    ushort* lA = &As[(w * 32) * 64];
    ushort* lB = &Bs[(w * 32) * 64];

    f32x4 acc[4][4] = {};

    for (int k0 = 0; k0 < Cn; k0 += 64) {
        __syncthreads();
#pragma unroll
        for (int t = 0; t < 4; ++t) {
            gl_lds16(gA + (size_t)t * 8 * Cn + k0, lA + t * 8 * 64);
            gl_lds16(gB + (size_t)t * 8 * Cn + k0, lB + t * 8 * 64);
        }
        __syncthreads();
#pragma unroll
        for (int ks = 0; ks < 2; ++ks) {
            const int xs = (((ks * 4 + qd) ^ (l15 & 7))) * 8;
            s16x8 af[4], bfr[4];
#pragma unroll
            for (int i = 0; i < 4; ++i) {
                af[i]  = *(const s16x8*)&As[(wm + i * 16 + l15) * 64 + xs];
                bfr[i] = *(const s16x8*)&Bs[(wn + i * 16 + l15) * 64 + xs];
            }
#pragma unroll
            for (int mt = 0; mt < 4; ++mt)
#pragma unroll
                for (int nt = 0; nt < 4; ++nt)
                    acc[mt][nt] = MFMA_BF16(af[mt], bfr[nt], acc[mt][nt]);
        }
    }

#pragma unroll
    for (int nt = 0; nt < 4; ++nt) {
        int n_g = n0 + wn + nt * 16 + l15;
        float bv = bias[n_g];
        int sel = n_g >> 10;
        int h = (n_g >> 6) & 15;
        int d = n_g & 63;
        ushort* O = (sel == 0) ? Qo : ((sel == 1) ? Ko : Vo);
        float scl = (sel == 0) ? SC : 1.0f;
#pragma unroll
        for (int mt = 0; mt < 4; ++mt) {
#pragma unroll
            for (int r = 0; r < 4; ++r) {
                int m_g = m0 + wm + mt * 16 + qd * 4 + r;
                int b = m_g >> 11, t = m_g & 2047;
                O[(((size_t)(b * Hn + h) * Tn + t) << 6) + d] =
                    f2bfu((acc[mt][nt][r] + bv) * scl);
            }
        }
    }
}

// ---------------------------------------------------------------------------
// Transposed MFMA flash attention, software-pipelined:
//  - grid (bh=64, pair=16): all 16 blocks of one bh share linear%8 -> one XCD
//  - double-buffered K/V LDS + register prefetch of tile kt+1 during compute
//  - ONE barrier per kt (write regs->LDS[buf], barrier, compute)
//  - Q pre-scaled (exp2-domain softmax), wave-uniform skip of o-rescale
// ---------------------------------------------------------------------------
__global__ __launch_bounds__(256) void attn_mfma(
    const ushort* __restrict__ Q, const ushort* __restrict__ K,
    const ushort* __restrict__ V, ushort* __restrict__ Y)
{
    __shared__ __align__(16) ushort Qs[64 * 64];     // Q tile; wave rows reused for P^T
    __shared__ __align__(16) ushort Ks[2][64 * 64];  // [key][d], double-buffered
    __shared__ __align__(16) ushort Vt[2][64 * 64];  // [d][key], double-buffered

    const int tid = threadIdx.x;
    const int bh = blockIdx.x, bx = blockIdx.y;
    const int w = tid >> 6, lane = tid & 63, l15 = lane & 15, qd = lane >> 4;
    const size_t base = (size_t)bh * Tn * Dn;
    const int srow = tid >> 2;          // 0..63
    const int c0 = (tid & 3) * 2;       // uint4 chunks c0, c0+1
    const int sw0 = srow * 64 + ((c0 ^ (srow & 7)) * 8);
    const int sw1 = srow * 64 + (((c0 + 1) ^ (srow & 7)) * 8);
    const int vk = (tid & 15) * 4, vd = (tid >> 4) * 4;
    const int vc = vk >> 3, vo = vk & 7;
    const int q_l = w * 16 + l15;
    const int frow = (w * 16 + l15) * 64;
    const int fx0 = ((0 * 4 + qd) ^ (l15 & 7)) * 8;
    const int fx1 = ((1 * 4 + qd) ^ (l15 & 7)) * 8;
    const int b = bh >> 4, h = bh & 15;

    uint4 kr0, kr1;
    ushort4 vr0, vr1, vr2, vr3;

#pragma unroll
    for (int half = 0; half < 2; ++half) {
        const int qt = half ? (31 - bx) : bx;
        __syncthreads();   // previous half's Qs(P) reads complete
        {
            const uint4* gq = (const uint4*)(Q + base + (size_t)(qt * 64 + srow) * Dn + c0 * 8);
            uint4 q0 = gq[0], q1 = gq[1];
            *(uint4*)&Qs[sw0] = q0;
            *(uint4*)&Qs[sw1] = q1;
        }
        // prefetch kt=0 (overlaps with Q staging barrier)
        {
            const uint4* gk = (const uint4*)(K + base + (size_t)(0 * 64 + srow) * Dn + c0 * 8);
            kr0 = gk[0]; kr1 = gk[1];
            const ushort* gv = V + base + (size_t)(0 * 64 + vk) * Dn + vd;
            vr0 = *(const ushort4*)(gv);
            vr1 = *(const ushort4*)(gv + Dn);
            vr2 = *(const ushort4*)(gv + 2 * Dn);
            vr3 = *(const ushort4*)(gv + 3 * Dn);
        }
        __syncthreads();
        s16x8 qf0 = *(const s16x8*)&Qs[frow + fx0];
        s16x8 qf1 = *(const s16x8*)&Qs[frow + fx1];

        float m_run = -1e30f, l_run = 0.f;
        f32x4 o[4] = {};   // O^T[d=dt*16+qd*4+r][q=l15]

        for (int kt = 0; kt <= qt; ++kt) {
            const int buf = kt & 1;
            // write prefetched tile -> LDS[buf]
            {
                ushort* kp = &Ks[buf][0];
                *(uint4*)&kp[sw0] = kr0;
                *(uint4*)&kp[sw1] = kr1;
                ushort4 t0, t1, t2, t3;
                t0.x = vr0.x; t0.y = vr1.x; t0.z = vr2.x; t0.w = vr3.x;
                t1.x = vr0.y; t1.y = vr1.y; t1.z = vr2.y; t1.w = vr3.y;
                t2.x = vr0.z; t2.y = vr1.z; t2.z = vr2.z; t2.w = vr3.z;
                t3.x = vr0.w; t3.y = vr1.w; t3.z = vr2.w; t3.w = vr3.w;
#pragma unroll
                for (int j = 0; j < 4; ++j) {
                    int r = vd + j;
                    ushort4 tj = (j == 0) ? t0 : (j == 1) ? t1 : (j == 2) ? t2 : t3;
                    *(ushort4*)&Vt[buf][r * 64 + ((vc ^ (r & 7)) * 8) + vo] = tj;
                }
            }
            __syncthreads();   // all writes to LDS[buf] visible; buf^1 free
            if (kt < qt) {     // prefetch kt+1 during compute
                const uint4* gk = (const uint4*)(K + base + (size_t)((kt + 1) * 64 + srow) * Dn + c0 * 8);
                kr0 = gk[0]; kr1 = gk[1];
                const ushort* gv = V + base + (size_t)((kt + 1) * 64 + vk) * Dn + vd;
                vr0 = *(const ushort4*)(gv);
                vr1 = *(const ushort4*)(gv + Dn);
                vr2 = *(const ushort4*)(gv + 2 * Dn);
                vr3 = *(const ushort4*)(gv + 3 * Dn);
            }

            // S^T = K·Q^T (already in exp2 domain via pre-scaled Q)
            f32x4 s[4] = {};
#pragma unroll
            for (int nt = 0; nt < 4; ++nt) {
                s16x8 kf = *(const s16x8*)&Ks[buf][(nt * 16 + l15) * 64 + fx0];
                s[nt] = MFMA_BF16(kf, qf0, s[nt]);
            }
#pragma unroll
            for (int nt = 0; nt < 4; ++nt) {
                s16x8 kf = *(const s16x8*)&Ks[buf][(nt * 16 + l15) * 64 + fx1];
                s[nt] = MFMA_BF16(kf, qf1, s[nt]);
            }

            if (kt == qt) {
#pragma unroll
                for (int nt = 0; nt < 4; ++nt)
#pragma unroll
                    for (int r = 0; r < 4; ++r)
                        if (nt * 16 + qd * 4 + r > q_l) s[nt][r] = -1e30f;
            }

            // online softmax over keys: 15 in-lane + 2 shuffles
            float mx = s[0][0];
#pragma unroll
            for (int nt = 0; nt < 4; ++nt)
#pragma unroll
                for (int r = 0; r < 4; ++r) mx = fmaxf(mx, s[nt][r]);
            mx = fmaxf(mx, __shfl_xor(mx, 16));
            mx = fmaxf(mx, __shfl_xor(mx, 32));

            if (__any(mx > m_run)) {
                float m_new = fmaxf(m_run, mx);
                float alpha = exp2f(m_run - m_new);
                m_run = m_new;
                l_run *= alpha;
#pragma unroll
                for (int dt = 0; dt < 4; ++dt)
#pragma unroll
                    for (int r = 0; r < 4; ++r) o[dt][r] *= alpha;
            }
            float ls = 0.f;
#pragma unroll
            for (int nt = 0; nt < 4; ++nt)
#pragma unroll
                for (int r = 0; r < 4; ++r) {
                    float p = exp2f(s[nt][r] - m_run);
                    s[nt][r] = p;
                    ls += p;
                }
            ls += __shfl_xor(ls, 16);
            ls += __shfl_xor(ls, 32);
            l_run += ls;

            // P^T -> wave-private LDS rows
#pragma unroll
            for (int nt = 0; nt < 4; ++nt) {
                ushort4 pk;
                pk.x = f2bfu(s[nt][0]); pk.y = f2bfu(s[nt][1]);
                pk.z = f2bfu(s[nt][2]); pk.w = f2bfu(s[nt][3]);
                const int pc = 2 * nt + (qd >> 1), po = (qd & 1) * 4;
                *(ushort4*)&Qs[frow + ((pc ^ (l15 & 7)) * 8) + po] = pk;
            }

            // O^T += V^T · P^T
            {
                s16x8 pb = *(const s16x8*)&Qs[frow + fx0];
#pragma unroll
                for (int dt = 0; dt < 4; ++dt) {
                    s16x8 vf = *(const s16x8*)&Vt[buf][(dt * 16 + l15) * 64 + fx0];
                    o[dt] = MFMA_BF16(vf, pb, o[dt]);
                }
                pb = *(const s16x8*)&Qs[frow + fx1];
#pragma unroll
                for (int dt = 0; dt < 4; ++dt) {
                    s16x8 vf = *(const s16x8*)&Vt[buf][(dt * 16 + l15) * 64 + fx1];
                    o[dt] = MFMA_BF16(vf, pb, o[dt]);
                }
            }
        }

        // epilogue: O^T[d][q=l15] -> Y[b, t=q_global, h*64+d]
        const float inv = 1.f / l_run;
        const int t_g = qt * 64 + w * 16 + l15;
        ushort* yp = Y + ((size_t)(b * Tn + t_g)) * Cn + h * Dn + qd * 4;
#pragma unroll
        for (int dt = 0; dt < 4; ++dt) {
            ushort4 pk;
            pk.x = f2bfu(o[dt][0] * inv);
            pk.y = f2bfu(o[dt][1] * inv);
            pk.z = f2bfu(o[dt][2] * inv);
            pk.w = f2bfu(o[dt][3] * inv);
            *(ushort4*)(yp + dt * 16) = pk;
        }
    }
}

// ---------------------------------------------------------------------------
// Proj GEMM: Y [8192][1024] bf16, Wt [1024][1024] bf16 -> out fp32
// ---------------------------------------------------------------------------
__global__ __launch_bounds__(256) void proj_gemm_mfma(
    const ushort* __restrict__ A, const ushort* __restrict__ Bt,
    const float* __restrict__ bias, float* __restrict__ out)
{
    __shared__ __align__(16) ushort As[128 * 64];
    __shared__ __align__(16) ushort Bs[128 * 64];
    const int tid = threadIdx.x;
    const int m0 = blockIdx.x * 128, n0 = blockIdx.y * 128;
    const int w = tid >> 6, lane = tid & 63, l15 = lane & 15, qd = lane >> 4;
    const int wm = (w >> 1) * 64, wn = (w & 1) * 64;
    const int lrow = lane >> 3;
    const int lchunk = (lane & 7) ^ (lrow & 7);

    const ushort* gA = A + (size_t)(m0 + w * 32 + lrow) * Cn + lchunk * 8;
    const ushort* gB = Bt + (size_t)(n0 + w * 32 + lrow) * Cn + lchunk * 8;
    ushort* lA = &As[(w * 32) * 64];
    ushort* lB = &Bs[(w * 32) * 64];

    f32x4 acc[4][4] = {};

    for (int k0 = 0; k0 < Cn; k0 += 64) {
        __syncthreads();
#pragma unroll
        for (int t = 0; t < 4; ++t) {
            gl_lds16(gA + (size_t)t * 8 * Cn + k0, lA + t * 8 * 64);
            gl_lds16(gB + (size_t)t * 8 * Cn + k0, lB + t * 8 * 64);
        }
        __syncthreads();
#pragma unroll
        for (int ks = 0; ks < 2; ++ks) {
            const int xs = (((ks * 4 + qd) ^ (l15 & 7))) * 8;
            s16x8 af[4], bfr[4];
#pragma unroll
            for (int i = 0; i < 4; ++i) {
                af[i]  = *(const s16x8*)&As[(wm + i * 16 + l15) * 64 + xs];
                bfr[i] = *(const s16x8*)&Bs[(wn + i * 16 + l15) * 64 + xs];
            }
#pragma unroll
            for (int mt = 0; mt < 4; ++mt)
#pragma unroll
                for (int nt = 0; nt < 4; ++nt)
                    acc[mt][nt] = MFMA_BF16(af[mt], bfr[nt], acc[mt][nt]);
        }
    }

#pragma unroll
    for (int nt = 0; nt < 4; ++nt) {
        int n_g = n0 + wn + nt * 16 + l15;
        float bv = bias[n_g];
#pragma unroll
        for (int mt = 0; mt < 4; ++mt) {
#pragma unroll
            for (int r = 0; r < 4; ++r) {
                int m_g = m0 + wm + mt * 16 + qd * 4 + r;
                out[(size_t)m_g * Cn + n_g] = acc[mt][nt][r] + bv;
            }
        }
    }
}

// ---------------------------------------------------------------------------
extern "C" void kernel_launch(void* const* d_in, const int* in_sizes, int n_in,
                              void* d_out, int out_size, void* d_ws, size_t ws_size,
                              hipStream_t stream) {
    const float* x      = (const float*)d_in[0];
    const float* W_attn = (const float*)d_in[1];
    const float* b_attn = (const float*)d_in[2];
    const float* W_proj = (const float*)d_in[3];
    const float* b_proj = (const float*)d_in[4];
    float* out = (float*)d_out;

    // ws: Q, K, V [B,H,T,D] bf16, Y [B,T,C] bf16
    constexpr size_t PER = (size_t)Mn * Cn;  // 8388608 elems
    ushort* Qb = (ushort*)d_ws;
    ushort* Kb = Qb + PER;
    ushort* Vb = Kb + PER;
    ushort* Yb = Vb + PER;

    // d_out doubles as pre-pass scratch (23 MB < 33.5 MB), dead before proj:
    ushort* WtA  = (ushort*)d_out;
    ushort* x_bf = WtA + (size_t)Nqkv * Cn;
    ushort* WtP  = Qb;   // reuses Q buffer (dead after attention)

    conv_bf16_kernel<<<1024, 256, 0, stream>>>(x, x_bf, (int)(PER / 4));
    transpose_cvt_kernel<<<dim3(Nqkv / 64, Cn / 64), 256, 0, stream>>>(
        W_attn, WtA, Cn, Nqkv);
    qkv_gemm_mfma<<<dim3(Mn / 128, Nqkv / 128), 256, 0, stream>>>(
        x_bf, WtA, b_attn, Qb, Kb, Vb);
    attn_mfma<<<dim3(Bn * Hn, 16), 256, 0, stream>>>(Qb, Kb, Vb, Yb);
    transpose_cvt_kernel<<<dim3(Cn / 64, Cn / 64), 256, 0, stream>>>(
        W_proj, WtP, Cn, Cn);
    proj_gemm_mfma<<<dim3(Mn / 128, Cn / 128), 256, 0, stream>>>(
        Yb, WtP, b_proj, out);
}